// Round 4
// baseline (330.130 us; speedup 1.0000x reference)
//
#include <hip/hip_runtime.h>
#include <cstddef>
#include <cstdint>

#define SCALE_WEIGHT 0.70710678118654752440f

static constexpr int B_ = 8, C_ = 512, T_ = 2048, S_ = 2048;
static constexpr size_t BCT_ = (size_t)B_ * C_ * T_;   // 8.4M  (ctx region elems)
static constexpr size_t BTS_ = (size_t)B_ * T_ * S_;   // 33.5M (attn region elems)

typedef _Float16 half_t;
typedef half_t half8  __attribute__((ext_vector_type(8)));
typedef half_t half4v __attribute__((ext_vector_type(4)));
typedef float  floatx4 __attribute__((ext_vector_type(4)));

// async global->LDS, 16B per lane. LDS dest = wave-uniform base + lane*16.
__device__ __forceinline__ void gload_lds16(const void* g, void* l) {
    __builtin_amdgcn_global_load_lds(
        (const __attribute__((address_space(1))) void*)g,
        (__attribute__((address_space(3))) void*)l, 16, 0, 0);
}

// ---------------------------------------------------------------------------
// transpose+convert: in [b][R][Cc] f32 -> out [b][Cc][R] f16. 64x64 tiles.
// ---------------------------------------------------------------------------
__global__ __launch_bounds__(256) void transpose_cvt_kernel(
    const float* __restrict__ in, half_t* __restrict__ out, int R, int Cc)
{
    __shared__ float tile[64][65];   // tile[c_local][r_local]
    const int b  = blockIdx.z;
    const int r0 = blockIdx.y * 64, c0 = blockIdx.x * 64;
    const float* ib = in + (size_t)b * R * Cc;
    half_t* ob = out + (size_t)b * R * Cc;
    const int t  = threadIdx.x;
    const int rr = t >> 4, cq = t & 15;
    #pragma unroll
    for (int i = 0; i < 4; ++i) {
        const int r = rr + i * 16;
        float4 v = *(const float4*)&ib[(size_t)(r0 + r) * Cc + c0 + cq * 4];
        tile[cq * 4 + 0][r] = v.x;
        tile[cq * 4 + 1][r] = v.y;
        tile[cq * 4 + 2][r] = v.z;
        tile[cq * 4 + 3][r] = v.w;
    }
    __syncthreads();
    const int cw = t >> 4, rq = (t & 15) * 4;
    #pragma unroll
    for (int i = 0; i < 4; ++i) {
        const int c = cw + i * 16;
        half4v h = {(half_t)tile[c][rq + 0], (half_t)tile[c][rq + 1],
                    (half_t)tile[c][rq + 2], (half_t)tile[c][rq + 3]};
        *(half4v*)&ob[(size_t)(c0 + c) * R + r0 + rq] = h;
    }
}

// ---------------------------------------------------------------------------
// plain convert f32 -> f16 (same layout), float4-granular
// ---------------------------------------------------------------------------
__global__ __launch_bounds__(256) void cvt_f32_f16_kernel(
    const float* __restrict__ in, half_t* __restrict__ out, int n4)
{
    const int stride = gridDim.x * blockDim.x;
    for (int i = blockIdx.x * blockDim.x + threadIdx.x; i < n4; i += stride) {
        float4 v = ((const float4*)in)[i];
        half4v h = {(half_t)v.x, (half_t)v.y, (half_t)v.z, (half_t)v.w};
        ((half4v*)out)[i] = h;
    }
}

// ---------------------------------------------------------------------------
// MFMA fp16 GEMM (r3 structure, proven): 128x128 tile, 4 waves, BK=64,
// double-buffered LDS, counted vmcnt(8). Used for K1 (EPI=1) and K4 (EPI=0).
// ---------------------------------------------------------------------------
template<int EPI>
__global__ __launch_bounds__(256) void gemm_f16_db_kernel(
    const half_t* __restrict__ A, const half_t* __restrict__ Bm,
    float* __restrict__ Cout, half_t* __restrict__ CoutH,
    const float* __restrict__ base, const float* __restrict__ bias,
    int M, int N, int K, size_t sA, size_t sB, size_t sC)
{
    __shared__ __align__(128) half_t As[2][128 * 64];
    __shared__ __align__(128) half_t Bs[2][128 * 64];

    const int tid  = threadIdx.x;
    const int lane = tid & 63, w = tid >> 6;
    const int wr = w >> 1, wc = w & 1;
    const int b  = blockIdx.z;
    const int m0 = blockIdx.y * 128, n0 = blockIdx.x * 128;

    const half_t* Ab = A  + (size_t)b * sA;
    const half_t* Bb = Bm + (size_t)b * sB;

    const int lr = lane >> 3;
    const int sw = (lane & 7) ^ lr;
    const half_t* aG[4]; const half_t* bG[4];
    int dOff[4];
    #pragma unroll
    for (int i = 0; i < 4; ++i) {
        const int r = w * 32 + i * 8 + lr;
        aG[i] = Ab + (size_t)(m0 + r) * K + sw * 8;
        bG[i] = Bb + (size_t)(n0 + r) * K + sw * 8;
        dOff[i] = (w * 32 + i * 8) * 128;
    }

    const int fr = lane & 15, kg = lane >> 4;
    int aoff[4], boff[4];
    #pragma unroll
    for (int mi = 0; mi < 4; ++mi) {
        const int m = wr * 64 + mi * 16 + fr;
        aoff[mi] = m * 128 + ((kg ^ (m & 7)) << 4);
    }
    #pragma unroll
    for (int nj = 0; nj < 4; ++nj) {
        const int n = wc * 64 + nj * 16 + fr;
        boff[nj] = n * 128 + ((kg ^ (n & 7)) << 4);
    }

    floatx4 acc[4][4];
    #pragma unroll
    for (int mi = 0; mi < 4; ++mi)
        #pragma unroll
        for (int nj = 0; nj < 4; ++nj)
            acc[mi][nj] = (floatx4){0.f, 0.f, 0.f, 0.f};

    auto STAGE = [&](int t, int pg) {
        const int k0 = t * 64;
        char* Ad = (char*)As[pg];
        char* Bd = (char*)Bs[pg];
        #pragma unroll
        for (int i = 0; i < 4; ++i) {
            gload_lds16(aG[i] + k0, Ad + dOff[i]);
            gload_lds16(bG[i] + k0, Bd + dOff[i]);
        }
    };

    auto COMPUTE = [&](int pg) {
        const char* Ar = (const char*)As[pg];
        const char* Br = (const char*)Bs[pg];
        #pragma unroll
        for (int kk = 0; kk < 2; ++kk) {
            half8 af[4], bf[4];
            #pragma unroll
            for (int mi = 0; mi < 4; ++mi)
                af[mi] = *(const half8*)(Ar + (aoff[mi] ^ (kk << 6)));
            #pragma unroll
            for (int nj = 0; nj < 4; ++nj)
                bf[nj] = *(const half8*)(Br + (boff[nj] ^ (kk << 6)));
            #pragma unroll
            for (int mi = 0; mi < 4; ++mi)
                #pragma unroll
                for (int nj = 0; nj < 4; ++nj)
                    acc[mi][nj] = __builtin_amdgcn_mfma_f32_16x16x32_f16(
                        af[mi], bf[nj], acc[mi][nj], 0, 0, 0);
        }
    };

    const int NT = K >> 6;
    STAGE(0, 0);
    int cur = 0;
    for (int t = 0; t < NT - 1; ++t) {
        STAGE(t + 1, cur ^ 1);
        asm volatile("s_waitcnt vmcnt(8)" ::: "memory");
        __builtin_amdgcn_s_barrier();
        __builtin_amdgcn_sched_barrier(0);
        COMPUTE(cur);
        asm volatile("s_waitcnt lgkmcnt(0)" ::: "memory");
        __builtin_amdgcn_sched_barrier(0);
        __builtin_amdgcn_s_barrier();
        __builtin_amdgcn_sched_barrier(0);
        cur ^= 1;
    }
    asm volatile("s_waitcnt vmcnt(0)" ::: "memory");
    __builtin_amdgcn_s_barrier();
    __builtin_amdgcn_sched_barrier(0);
    COMPUTE(cur);

    if constexpr (EPI == 0) {
        float* Cb = Cout + (size_t)b * sC;
        #pragma unroll
        for (int mi = 0; mi < 4; ++mi) {
            const int row = m0 + wr * 64 + mi * 16 + (lane >> 4) * 4;
            #pragma unroll
            for (int nj = 0; nj < 4; ++nj) {
                const int col = n0 + wc * 64 + nj * 16 + (lane & 15);
                #pragma unroll
                for (int r = 0; r < 4; ++r)
                    Cb[(size_t)(row + r) * N + col] = acc[mi][nj][r];
            }
        }
    } else {
        half_t* Cb = CoutH + (size_t)b * sC;
        #pragma unroll
        for (int nj = 0; nj < 4; ++nj) {
            const int col = n0 + wc * 64 + nj * 16 + (lane & 15);
            const float bn = bias[col];
            const float* bp = base + ((size_t)b * N + col) * (size_t)M;
            #pragma unroll
            for (int mi = 0; mi < 4; ++mi) {
                const int row = m0 + wr * 64 + mi * 16 + (lane >> 4) * 4;
                #pragma unroll
                for (int r = 0; r < 4; ++r) {
                    float v = (acc[mi][nj][r] + bn + bp[row + r]) * SCALE_WEIGHT;
                    Cb[(size_t)(row + r) * N + col] = (half_t)v;
                }
            }
        }
    }
}

// ---------------------------------------------------------------------------
// k23: fused logits-GEMM + online softmax. One block = 64 t-rows of one batch.
// A (tgtT 64x512 f16) resident in LDS; loop 16 s-tiles of topT, streaming
// k-chunks [128s][64k] with r3's counted-vmcnt double-buffer. Online row
// stats (m, sigma) in LDS; p = exp(l - m_used) stored f16 to pws. Phase 2
// rescales by exp(m_used - m_fin)/sigma, writes attn f32 + attnh f16.
// Grid (x=b=8, y=tt=32): linear%8==b -> each batch pinned to one XCD (L2 reuse).
// ---------------------------------------------------------------------------
__global__ __launch_bounds__(512) void k23_fused_kernel(
    const half_t* __restrict__ tgtT, const half_t* __restrict__ topT,
    float* __restrict__ attnf, half_t* __restrict__ attnh,
    half_t* __restrict__ pws)
{
    __shared__ __align__(128) half_t Atile[64 * 512];   // 64KB resident A
    __shared__ __align__(128) half_t Bbuf[2][128 * 64]; // 2x16KB stream B
    __shared__ __align__(128) half_t ptile[64 * 128];   // 16KB p staging
    __shared__ float mu[16 * 64];                       // m_used[st][row]
    __shared__ float msh[64], ssh[64];                  // running max / sum
    __shared__ float pmax[4][64], psum[4][64];          // per-colwave partials

    const int tid = threadIdx.x, lane = tid & 63, w = tid >> 6;
    const int wr = w >> 2, wc = w & 3;                  // 2x4 wave grid
    const int b = blockIdx.x, tt = blockIdx.y;
    const int fr = lane & 15, kg = lane >> 4;
    const int q4 = (lane >> 4) << 2;

    const half_t* Ab = tgtT + ((size_t)(b * T_ + tt * 64)) * C_;
    const half_t* Bb = topT + (size_t)b * S_ * C_;
    half_t* pblk = pws + ((size_t)(b * 32 + tt)) * 64 * 2048;

    if (tid < 64) { msh[tid] = -3.0e38f; ssh[tid] = 0.f; }

    // stage resident A: wave w stages rows w*8..w*8+7 (1KB row each)
    #pragma unroll
    for (int i = 0; i < 8; ++i) {
        const int row = w * 8 + i;
        gload_lds16(Ab + (size_t)row * C_ + ((lane ^ (row & 7)) << 3),
                    (char*)Atile + row * 1024);
    }

    auto STAGE_B = [&](int q, int pg) {
        const int s0 = (q >> 3) * 128, k0 = (q & 7) * 64;
        char* dst = (char*)Bbuf[pg];
        #pragma unroll
        for (int j = 0; j < 2; ++j) {
            const int r8 = w * 16 + j * 8;
            gload_lds16(Bb + (size_t)(s0 + r8 + (lane >> 3)) * C_ + k0 +
                            (((lane & 7) ^ (lane >> 3)) << 3),
                        dst + r8 * 128);
        }
    };

    STAGE_B(0, 0);
    int buf = 0;

    for (int st = 0; st < 16; ++st) {
        floatx4 acc[2][2];
        #pragma unroll
        for (int mi = 0; mi < 2; ++mi)
            #pragma unroll
            for (int nj = 0; nj < 2; ++nj)
                acc[mi][nj] = (floatx4){0.f, 0.f, 0.f, 0.f};

        for (int kc = 0; kc < 8; ++kc) {
            const int q = st * 8 + kc;
            if (q < 127) {
                STAGE_B(q + 1, buf ^ 1);
                asm volatile("s_waitcnt vmcnt(2)" ::: "memory");
            } else {
                asm volatile("s_waitcnt vmcnt(0)" ::: "memory");
            }
            __builtin_amdgcn_s_barrier();
            __builtin_amdgcn_sched_barrier(0);

            const char* Ar = (const char*)Atile;
            const char* Br = (const char*)Bbuf[buf];
            #pragma unroll
            for (int kk = 0; kk < 2; ++kk) {
                half8 af[2], bf[2];
                #pragma unroll
                for (int mi = 0; mi < 2; ++mi) {
                    const int m = wr * 32 + mi * 16 + fr;
                    af[mi] = *(const half8*)(Ar + m * 1024 +
                              (((kc * 8 + kk * 4 + kg) ^ (m & 7)) << 4));
                }
                #pragma unroll
                for (int nj = 0; nj < 2; ++nj) {
                    const int n = wc * 32 + nj * 16 + fr;
                    bf[nj] = *(const half8*)(Br + n * 128 +
                              (((kk * 4 + kg) ^ (n & 7)) << 4));
                }
                #pragma unroll
                for (int mi = 0; mi < 2; ++mi)
                    #pragma unroll
                    for (int nj = 0; nj < 2; ++nj)
                        acc[mi][nj] = __builtin_amdgcn_mfma_f32_16x16x32_f16(
                            af[mi], bf[nj], acc[mi][nj], 0, 0, 0);
            }

            asm volatile("s_waitcnt lgkmcnt(0)" ::: "memory");
            __builtin_amdgcn_sched_barrier(0);
            __builtin_amdgcn_s_barrier();
            __builtin_amdgcn_sched_barrier(0);
            buf ^= 1;
        }

        // ---- online softmax update for this s-tile ----
        // per-lane rows: wr*32 + mi*16 + q4 + r ; cols: wc*32 + nj*16 + fr
        #pragma unroll
        for (int mi = 0; mi < 2; ++mi)
            #pragma unroll
            for (int r = 0; r < 4; ++r) {
                float v = fmaxf(acc[mi][0][r], acc[mi][1][r]);
                v = fmaxf(v, __shfl_xor(v, 1));
                v = fmaxf(v, __shfl_xor(v, 2));
                v = fmaxf(v, __shfl_xor(v, 4));
                v = fmaxf(v, __shfl_xor(v, 8));
                if (fr == 0) pmax[wc][wr * 32 + mi * 16 + q4 + r] = v;
            }
        __syncthreads();

        float scaleReg = 0.f;
        if (tid < 64) {
            float tm = fmaxf(fmaxf(pmax[0][tid], pmax[1][tid]),
                             fmaxf(pmax[2][tid], pmax[3][tid]));
            float mo = msh[tid];
            float mn = fmaxf(mo, tm);
            msh[tid] = mn;
            mu[st * 64 + tid] = mn;
            scaleReg = __expf(mo - mn);
        }
        __syncthreads();

        #pragma unroll
        for (int mi = 0; mi < 2; ++mi)
            #pragma unroll
            for (int r = 0; r < 4; ++r) {
                const int row = wr * 32 + mi * 16 + q4 + r;
                const float mn = msh[row];
                float p0 = __expf(acc[mi][0][r] - mn);
                float p1 = __expf(acc[mi][1][r] - mn);
                ptile[row * 128 + wc * 32 + fr]      = (half_t)p0;
                ptile[row * 128 + wc * 32 + 16 + fr] = (half_t)p1;
                float s = p0 + p1;
                s += __shfl_xor(s, 1);
                s += __shfl_xor(s, 2);
                s += __shfl_xor(s, 4);
                s += __shfl_xor(s, 8);
                if (fr == 0) psum[wc][row] = s;
            }
        __syncthreads();

        if (tid < 64)
            ssh[tid] = ssh[tid] * scaleReg +
                       psum[0][tid] + psum[1][tid] + psum[2][tid] + psum[3][tid];

        // coalesced p-store: 64x128 f16 tile -> pws row-major [64][2048]
        {
            const int row = tid >> 3, cg = (tid & 7) * 16;
            half8 v0 = *(const half8*)&ptile[row * 128 + cg];
            half8 v1 = *(const half8*)&ptile[row * 128 + cg + 8];
            *(half8*)&pblk[(size_t)row * 2048 + st * 128 + cg]     = v0;
            *(half8*)&pblk[(size_t)row * 2048 + st * 128 + cg + 8] = v1;
        }
    }

    // ---- phase 2: rescale + emit attn f32 and attnh f16 ----
    __syncthreads();
    for (int i = tid; i < 1024; i += 512) {
        const int row = i & 63;
        mu[i] = __expf(mu[i] - msh[row]) / ssh[row];
    }
    __syncthreads();

    #pragma unroll 1
    for (int it = 0; it < 16; ++it) {
        const int e = (it * 512 + tid) * 16;
        const int row = e >> 11, col = e & 2047;
        const float f = mu[(col >> 7) * 64 + row];
        half8 v0 = *(const half8*)&pblk[(size_t)row * 2048 + col];
        half8 v1 = *(const half8*)&pblk[(size_t)row * 2048 + col + 8];
        const size_t oidx = ((size_t)(b * T_ + tt * 64 + row)) * S_ + col;
        float4 o; half8 h0, h1;
        float a0 = (float)v0[0] * f, a1 = (float)v0[1] * f;
        float a2 = (float)v0[2] * f, a3 = (float)v0[3] * f;
        o = (float4){a0, a1, a2, a3};
        *(float4*)&attnf[oidx] = o;
        h0[0] = (half_t)a0; h0[1] = (half_t)a1; h0[2] = (half_t)a2; h0[3] = (half_t)a3;
        a0 = (float)v0[4] * f; a1 = (float)v0[5] * f;
        a2 = (float)v0[6] * f; a3 = (float)v0[7] * f;
        o = (float4){a0, a1, a2, a3};
        *(float4*)&attnf[oidx + 4] = o;
        h0[4] = (half_t)a0; h0[5] = (half_t)a1; h0[6] = (half_t)a2; h0[7] = (half_t)a3;
        a0 = (float)v1[0] * f; a1 = (float)v1[1] * f;
        a2 = (float)v1[2] * f; a3 = (float)v1[3] * f;
        o = (float4){a0, a1, a2, a3};
        *(float4*)&attnf[oidx + 8] = o;
        h1[0] = (half_t)a0; h1[1] = (half_t)a1; h1[2] = (half_t)a2; h1[3] = (half_t)a3;
        a0 = (float)v1[4] * f; a1 = (float)v1[5] * f;
        a2 = (float)v1[6] * f; a3 = (float)v1[7] * f;
        o = (float4){a0, a1, a2, a3};
        *(float4*)&attnf[oidx + 12] = o;
        h1[4] = (half_t)a0; h1[5] = (half_t)a1; h1[6] = (half_t)a2; h1[7] = (half_t)a3;
        *(half8*)&attnh[oidx]     = h0;
        *(half8*)&attnh[oidx + 8] = h1;
    }
}

extern "C" void kernel_launch(void* const* d_in, const int* in_sizes, int n_in,
                              void* d_out, int out_size, void* d_ws, size_t ws_size,
                              hipStream_t stream) {
    const float* base = (const float*)d_in[0];  // [B,C,T,1]
    const float* x    = (const float*)d_in[1];  // [B,C,T,1]
    const float* top  = (const float*)d_in[2];  // [B,C,S]
    const float* comb = (const float*)d_in[3];  // [B,C,S]
    const float* W    = (const float*)d_in[4];  // [C,C]
    const float* bias = (const float*)d_in[5];  // [C]

    float* out   = (float*)d_out;
    float* ctx   = out;          // [B,C,T] final context output (f32, 33.5MB)
    float* attnf = out + BCT_;   // [B,T,S] attn output (f32, 134MB)

    // fp16 staging overlaid on the ctx region (dead before K4 rewrites it):
    half_t* xT   = (half_t*)d_out;        // [B][T][C] f16, bytes [0, 16.8M)
    half_t* topT = xT + BCT_;             // [B][S][C] f16, bytes [16.8M, 33.5M)

    // ws layout (168.3MB total):
    half_t* pws   = (half_t*)d_ws;                    // [256][64][2048] f16, 67MB
    half_t* attnh = pws + (size_t)256 * 64 * 2048;    // [B][T][S] f16, 67MB
    half_t* combh = attnh + BTS_;                     // [B][C][S] f16, 16.8MB
    half_t* Wh    = combh + (size_t)B_ * C_ * S_;     // [C][C] f16, 0.5MB
    half_t* tgtT  = Wh + (size_t)C_ * C_;             // [B][T][C] f16, 16.8MB

    // converts / transposes
    transpose_cvt_kernel<<<dim3(T_ / 64, C_ / 64, B_), 256, 0, stream>>>(x, xT, C_, T_);
    transpose_cvt_kernel<<<dim3(S_ / 64, C_ / 64, B_), 256, 0, stream>>>(top, topT, C_, S_);
    cvt_f32_f16_kernel<<<2048, 256, 0, stream>>>(comb, combh, (int)((size_t)B_ * C_ * S_ / 4));
    cvt_f32_f16_kernel<<<256, 256, 0, stream>>>(W, Wh, C_ * C_ / 4);

    // K1: tgtT[b][t][o] = (x^T W^T + b + base)*SCALE   M=T,N=C,K=C
    gemm_f16_db_kernel<1><<<dim3(C_ / 128, T_ / 128, B_), 256, 0, stream>>>(
        xT, Wh, nullptr, tgtT, base, bias,
        T_, C_, C_, (size_t)T_ * C_, 0, (size_t)T_ * C_);

    // K2+K3 fused: logits GEMM + online softmax -> attn f32 + attnh f16
    k23_fused_kernel<<<dim3(B_, T_ / 64), 512, 0, stream>>>(
        tgtT, topT, attnf, attnh, pws);

    // K4: ctx[b][c][t] = combh . attnh                 M=C,N=T,K=S
    gemm_f16_db_kernel<0><<<dim3(T_ / 128, C_ / 128, B_), 256, 0, stream>>>(
        combh, attnh, ctx, nullptr, nullptr, nullptr,
        C_, T_, S_, (size_t)C_ * S_, (size_t)T_ * S_, (size_t)C_ * T_);
}

// Round 5
// 261.296 us; speedup vs baseline: 1.2634x; 1.2634x over previous
//
#include <hip/hip_runtime.h>
#include <cstddef>
#include <cstdint>

#define SCALE_WEIGHT 0.70710678118654752440f

static constexpr int B_ = 8, C_ = 512, T_ = 2048, S_ = 2048;
static constexpr size_t BCT_ = (size_t)B_ * C_ * T_;   // 8.4M  (ctx region elems)
static constexpr size_t BTS_ = (size_t)B_ * T_ * S_;   // 33.5M (attn region elems)

typedef _Float16 half_t;
typedef half_t half8  __attribute__((ext_vector_type(8)));
typedef half_t half4v __attribute__((ext_vector_type(4)));
typedef float  floatx4 __attribute__((ext_vector_type(4)));

// async global->LDS, 16B per lane. LDS dest = wave-uniform base + lane*16.
__device__ __forceinline__ void gload_lds16(const void* g, void* l) {
    __builtin_amdgcn_global_load_lds(
        (const __attribute__((address_space(1))) void*)g,
        (__attribute__((address_space(3))) void*)l, 16, 0, 0);
}

// ---------------------------------------------------------------------------
// merged transpose+convert for x and top: [b][512][2048] f32 -> [b][2048][512] f16
// z in [0,16): z<8 -> x, z>=8 -> top.
// ---------------------------------------------------------------------------
__global__ __launch_bounds__(256) void transpose2_cvt_kernel(
    const float* __restrict__ x, const float* __restrict__ top,
    half_t* __restrict__ xT, half_t* __restrict__ topT)
{
    __shared__ float tile[64][65];   // tile[c_local][r_local]
    const int z = blockIdx.z;
    const float* in = (z < 8) ? x : top;
    half_t* outp = (z < 8) ? xT : topT;
    const int b  = z & 7;
    const int r0 = blockIdx.y * 64, c0 = blockIdx.x * 64;
    const float* ib = in + (size_t)b * C_ * T_;
    half_t* ob = outp + (size_t)b * C_ * T_;
    const int t  = threadIdx.x;
    const int rr = t >> 4, cq = t & 15;
    #pragma unroll
    for (int i = 0; i < 4; ++i) {
        const int r = rr + i * 16;
        float4 v = *(const float4*)&ib[(size_t)(r0 + r) * T_ + c0 + cq * 4];
        tile[cq * 4 + 0][r] = v.x;
        tile[cq * 4 + 1][r] = v.y;
        tile[cq * 4 + 2][r] = v.z;
        tile[cq * 4 + 3][r] = v.w;
    }
    __syncthreads();
    const int cw = t >> 4, rq = (t & 15) * 4;
    #pragma unroll
    for (int i = 0; i < 4; ++i) {
        const int c = cw + i * 16;
        half4v h = {(half_t)tile[c][rq + 0], (half_t)tile[c][rq + 1],
                    (half_t)tile[c][rq + 2], (half_t)tile[c][rq + 3]};
        *(half4v*)&ob[(size_t)(c0 + c) * C_ + r0 + rq] = h;
    }
}

// ---------------------------------------------------------------------------
// merged convert f32 -> f16 for comb and W
// ---------------------------------------------------------------------------
__global__ __launch_bounds__(256) void cvt2_f32_f16_kernel(
    const float* __restrict__ comb, half_t* __restrict__ combh,
    const float* __restrict__ W, half_t* __restrict__ Wh,
    int n4a, int n4tot)
{
    const int stride = gridDim.x * blockDim.x;
    for (int i = blockIdx.x * blockDim.x + threadIdx.x; i < n4tot; i += stride) {
        const float4* src; half4v* dst; int j;
        if (i < n4a) { src = (const float4*)comb; dst = (half4v*)combh; j = i; }
        else         { src = (const float4*)W;    dst = (half4v*)Wh;    j = i - n4a; }
        float4 v = src[j];
        dst[j] = (half4v){(half_t)v.x, (half_t)v.y, (half_t)v.z, (half_t)v.w};
    }
}

// ---------------------------------------------------------------------------
// MFMA fp16 GEMM (r3 structure, proven): 128x128 tile, 4 waves, BK=64,
// double-buffered LDS, counted vmcnt(8). Used for K1 (EPI=1) and K4 (EPI=0).
// ---------------------------------------------------------------------------
template<int EPI>
__global__ __launch_bounds__(256) void gemm_f16_db_kernel(
    const half_t* __restrict__ A, const half_t* __restrict__ Bm,
    float* __restrict__ Cout, half_t* __restrict__ CoutH,
    const float* __restrict__ base, const float* __restrict__ bias,
    int M, int N, int K, size_t sA, size_t sB, size_t sC)
{
    __shared__ __align__(128) half_t As[2][128 * 64];
    __shared__ __align__(128) half_t Bs[2][128 * 64];

    const int tid  = threadIdx.x;
    const int lane = tid & 63, w = tid >> 6;
    const int wr = w >> 1, wc = w & 1;
    const int b  = blockIdx.z;
    const int m0 = blockIdx.y * 128, n0 = blockIdx.x * 128;

    const half_t* Ab = A  + (size_t)b * sA;
    const half_t* Bb = Bm + (size_t)b * sB;

    const int lr = lane >> 3;
    const int sw = (lane & 7) ^ lr;
    const half_t* aG[4]; const half_t* bG[4];
    int dOff[4];
    #pragma unroll
    for (int i = 0; i < 4; ++i) {
        const int r = w * 32 + i * 8 + lr;
        aG[i] = Ab + (size_t)(m0 + r) * K + sw * 8;
        bG[i] = Bb + (size_t)(n0 + r) * K + sw * 8;
        dOff[i] = (w * 32 + i * 8) * 128;
    }

    const int fr = lane & 15, kg = lane >> 4;
    int aoff[4], boff[4];
    #pragma unroll
    for (int mi = 0; mi < 4; ++mi) {
        const int m = wr * 64 + mi * 16 + fr;
        aoff[mi] = m * 128 + ((kg ^ (m & 7)) << 4);
    }
    #pragma unroll
    for (int nj = 0; nj < 4; ++nj) {
        const int n = wc * 64 + nj * 16 + fr;
        boff[nj] = n * 128 + ((kg ^ (n & 7)) << 4);
    }

    floatx4 acc[4][4];
    #pragma unroll
    for (int mi = 0; mi < 4; ++mi)
        #pragma unroll
        for (int nj = 0; nj < 4; ++nj)
            acc[mi][nj] = (floatx4){0.f, 0.f, 0.f, 0.f};

    auto STAGE = [&](int t, int pg) {
        const int k0 = t * 64;
        char* Ad = (char*)As[pg];
        char* Bd = (char*)Bs[pg];
        #pragma unroll
        for (int i = 0; i < 4; ++i) {
            gload_lds16(aG[i] + k0, Ad + dOff[i]);
            gload_lds16(bG[i] + k0, Bd + dOff[i]);
        }
    };

    auto COMPUTE = [&](int pg) {
        const char* Ar = (const char*)As[pg];
        const char* Br = (const char*)Bs[pg];
        #pragma unroll
        for (int kk = 0; kk < 2; ++kk) {
            half8 af[4], bf[4];
            #pragma unroll
            for (int mi = 0; mi < 4; ++mi)
                af[mi] = *(const half8*)(Ar + (aoff[mi] ^ (kk << 6)));
            #pragma unroll
            for (int nj = 0; nj < 4; ++nj)
                bf[nj] = *(const half8*)(Br + (boff[nj] ^ (kk << 6)));
            #pragma unroll
            for (int mi = 0; mi < 4; ++mi)
                #pragma unroll
                for (int nj = 0; nj < 4; ++nj)
                    acc[mi][nj] = __builtin_amdgcn_mfma_f32_16x16x32_f16(
                        af[mi], bf[nj], acc[mi][nj], 0, 0, 0);
        }
    };

    const int NT = K >> 6;
    STAGE(0, 0);
    int cur = 0;
    for (int t = 0; t < NT - 1; ++t) {
        STAGE(t + 1, cur ^ 1);
        asm volatile("s_waitcnt vmcnt(8)" ::: "memory");
        __builtin_amdgcn_s_barrier();
        __builtin_amdgcn_sched_barrier(0);
        COMPUTE(cur);
        asm volatile("s_waitcnt lgkmcnt(0)" ::: "memory");
        __builtin_amdgcn_sched_barrier(0);
        __builtin_amdgcn_s_barrier();
        __builtin_amdgcn_sched_barrier(0);
        cur ^= 1;
    }
    asm volatile("s_waitcnt vmcnt(0)" ::: "memory");
    __builtin_amdgcn_s_barrier();
    __builtin_amdgcn_sched_barrier(0);
    COMPUTE(cur);

    if constexpr (EPI == 0) {
        float* Cb = Cout + (size_t)b * sC;
        #pragma unroll
        for (int mi = 0; mi < 4; ++mi) {
            const int row = m0 + wr * 64 + mi * 16 + (lane >> 4) * 4;
            #pragma unroll
            for (int nj = 0; nj < 4; ++nj) {
                const int col = n0 + wc * 64 + nj * 16 + (lane & 15);
                #pragma unroll
                for (int r = 0; r < 4; ++r)
                    Cb[(size_t)(row + r) * N + col] = acc[mi][nj][r];
            }
        }
    } else {
        half_t* Cb = CoutH + (size_t)b * sC;
        #pragma unroll
        for (int nj = 0; nj < 4; ++nj) {
            const int col = n0 + wc * 64 + nj * 16 + (lane & 15);
            const float bn = bias[col];
            const float* bp = base + ((size_t)b * N + col) * (size_t)M;
            #pragma unroll
            for (int mi = 0; mi < 4; ++mi) {
                const int row = m0 + wr * 64 + mi * 16 + (lane >> 4) * 4;
                #pragma unroll
                for (int r = 0; r < 4; ++r) {
                    float v = (acc[mi][nj][r] + bn + bp[row + r]) * SCALE_WEIGHT;
                    Cb[(size_t)(row + r) * N + col] = (half_t)v;
                }
            }
        }
    }
}

// ---------------------------------------------------------------------------
// k2p: logits GEMM (R3 structure, M=T N=S K=C) + per-tile softmax prep.
// Epilogue: per 128-col tile, row-max m_st; stores p = exp(l - m_st) f16 and
// (m_st, sigma_st) per row to stats arrays. No f32 logits materialization.
// ---------------------------------------------------------------------------
__global__ __launch_bounds__(256) void k2p_kernel(
    const half_t* __restrict__ A, const half_t* __restrict__ Bm,
    half_t* __restrict__ P, float* __restrict__ mArr, float* __restrict__ sArr)
{
    __shared__ __align__(128) half_t As[2][128 * 64];
    __shared__ __align__(128) half_t Bs[2][128 * 64];
    __shared__ float rmax[2][128];
    __shared__ float rsum[2][128];

    const int tid  = threadIdx.x;
    const int lane = tid & 63, w = tid >> 6;
    const int wr = w >> 1, wc = w & 1;
    const int b  = blockIdx.z;
    const int m0 = blockIdx.y * 128, n0 = blockIdx.x * 128;
    constexpr int K = C_;

    const half_t* Ab = A  + (size_t)b * T_ * C_;
    const half_t* Bb = Bm + (size_t)b * S_ * C_;

    const int lr = lane >> 3;
    const int sw = (lane & 7) ^ lr;
    const half_t* aG[4]; const half_t* bG[4];
    int dOff[4];
    #pragma unroll
    for (int i = 0; i < 4; ++i) {
        const int r = w * 32 + i * 8 + lr;
        aG[i] = Ab + (size_t)(m0 + r) * K + sw * 8;
        bG[i] = Bb + (size_t)(n0 + r) * K + sw * 8;
        dOff[i] = (w * 32 + i * 8) * 128;
    }

    const int fr = lane & 15, kg = lane >> 4;
    const int q4 = kg * 4;
    int aoff[4], boff[4];
    #pragma unroll
    for (int mi = 0; mi < 4; ++mi) {
        const int m = wr * 64 + mi * 16 + fr;
        aoff[mi] = m * 128 + ((kg ^ (m & 7)) << 4);
    }
    #pragma unroll
    for (int nj = 0; nj < 4; ++nj) {
        const int n = wc * 64 + nj * 16 + fr;
        boff[nj] = n * 128 + ((kg ^ (n & 7)) << 4);
    }

    floatx4 acc[4][4];
    #pragma unroll
    for (int mi = 0; mi < 4; ++mi)
        #pragma unroll
        for (int nj = 0; nj < 4; ++nj)
            acc[mi][nj] = (floatx4){0.f, 0.f, 0.f, 0.f};

    auto STAGE = [&](int t, int pg) {
        const int k0 = t * 64;
        char* Ad = (char*)As[pg];
        char* Bd = (char*)Bs[pg];
        #pragma unroll
        for (int i = 0; i < 4; ++i) {
            gload_lds16(aG[i] + k0, Ad + dOff[i]);
            gload_lds16(bG[i] + k0, Bd + dOff[i]);
        }
    };

    auto COMPUTE = [&](int pg) {
        const char* Ar = (const char*)As[pg];
        const char* Br = (const char*)Bs[pg];
        #pragma unroll
        for (int kk = 0; kk < 2; ++kk) {
            half8 af[4], bf[4];
            #pragma unroll
            for (int mi = 0; mi < 4; ++mi)
                af[mi] = *(const half8*)(Ar + (aoff[mi] ^ (kk << 6)));
            #pragma unroll
            for (int nj = 0; nj < 4; ++nj)
                bf[nj] = *(const half8*)(Br + (boff[nj] ^ (kk << 6)));
            #pragma unroll
            for (int mi = 0; mi < 4; ++mi)
                #pragma unroll
                for (int nj = 0; nj < 4; ++nj)
                    acc[mi][nj] = __builtin_amdgcn_mfma_f32_16x16x32_f16(
                        af[mi], bf[nj], acc[mi][nj], 0, 0, 0);
        }
    };

    constexpr int NT = K >> 6;   // 8
    STAGE(0, 0);
    int cur = 0;
    for (int t = 0; t < NT - 1; ++t) {
        STAGE(t + 1, cur ^ 1);
        asm volatile("s_waitcnt vmcnt(8)" ::: "memory");
        __builtin_amdgcn_s_barrier();
        __builtin_amdgcn_sched_barrier(0);
        COMPUTE(cur);
        asm volatile("s_waitcnt lgkmcnt(0)" ::: "memory");
        __builtin_amdgcn_sched_barrier(0);
        __builtin_amdgcn_s_barrier();
        __builtin_amdgcn_sched_barrier(0);
        cur ^= 1;
    }
    asm volatile("s_waitcnt vmcnt(0)" ::: "memory");
    __builtin_amdgcn_s_barrier();
    __builtin_amdgcn_sched_barrier(0);
    COMPUTE(cur);

    // ---- epilogue: per-tile row stats + f16 p store ----
    // rows held per thread: wr*64 + mi*16 + q4 + r ; cols: n0 + wc*64 + nj*16 + fr
    #pragma unroll
    for (int mi = 0; mi < 4; ++mi) {
        #pragma unroll
        for (int r = 0; r < 4; ++r) {
            float v = fmaxf(fmaxf(acc[mi][0][r], acc[mi][1][r]),
                            fmaxf(acc[mi][2][r], acc[mi][3][r]));
            v = fmaxf(v, __shfl_xor(v, 1));
            v = fmaxf(v, __shfl_xor(v, 2));
            v = fmaxf(v, __shfl_xor(v, 4));
            v = fmaxf(v, __shfl_xor(v, 8));
            if (fr == 0) rmax[wc][wr * 64 + mi * 16 + q4 + r] = v;
        }
    }
    __syncthreads();

    half_t* Pb = P + ((size_t)(b * T_ + m0)) * S_;
    #pragma unroll
    for (int mi = 0; mi < 4; ++mi) {
        #pragma unroll
        for (int r = 0; r < 4; ++r) {
            const int row = wr * 64 + mi * 16 + q4 + r;
            const float mC = fmaxf(rmax[0][row], rmax[1][row]);
            float s = 0.f;
            #pragma unroll
            for (int nj = 0; nj < 4; ++nj) {
                float pv = __expf(acc[mi][nj][r] - mC);
                s += pv;
                Pb[(size_t)row * S_ + n0 + wc * 64 + nj * 16 + fr] = (half_t)pv;
            }
            s += __shfl_xor(s, 1);
            s += __shfl_xor(s, 2);
            s += __shfl_xor(s, 4);
            s += __shfl_xor(s, 8);
            if (fr == 0) rsum[wc][row] = s;
        }
    }
    __syncthreads();

    if (tid < 128) {
        const float m = fmaxf(rmax[0][tid], rmax[1][tid]);
        const float s = rsum[0][tid] + rsum[1][tid];
        const size_t si = ((size_t)(b * 16 + (n0 >> 7))) * T_ + m0 + tid;
        mArr[si] = m;
        sArr[si] = s;
    }
}

// ---------------------------------------------------------------------------
// k3b: per-row normalize. Combine 16 tile-stats exactly, scale p, write
// attn f32 (output) + attnh f16 (K4 operand). One block per (b,t) row.
// ---------------------------------------------------------------------------
__global__ __launch_bounds__(256) void k3b_kernel(
    const half_t* __restrict__ P, const float* __restrict__ mArr,
    const float* __restrict__ sArr, float* __restrict__ attnf,
    half_t* __restrict__ attnh)
{
    const int bid = blockIdx.x;
    const int b = bid >> 11, t = bid & 2047;
    const int tid = threadIdx.x;

    float mfin = -3.0e38f;
    #pragma unroll
    for (int j = 0; j < 16; ++j)
        mfin = fmaxf(mfin, mArr[((size_t)(b * 16 + j)) * T_ + t]);
    float sig = 0.f;
    #pragma unroll
    for (int j = 0; j < 16; ++j)
        sig += sArr[((size_t)(b * 16 + j)) * T_ + t] *
               __expf(mArr[((size_t)(b * 16 + j)) * T_ + t] - mfin);
    const float inv = 1.f / sig;
    const float f = __expf(mArr[((size_t)(b * 16 + (tid >> 4))) * T_ + t] - mfin) * inv;

    const size_t rb = (size_t)bid * S_ + tid * 8;
    half8 v = *(const half8*)&P[rb];
    float a0 = (float)v[0] * f, a1 = (float)v[1] * f;
    float a2 = (float)v[2] * f, a3 = (float)v[3] * f;
    float a4 = (float)v[4] * f, a5 = (float)v[5] * f;
    float a6 = (float)v[6] * f, a7 = (float)v[7] * f;
    *(float4*)&attnf[rb]     = (float4){a0, a1, a2, a3};
    *(float4*)&attnf[rb + 4] = (float4){a4, a5, a6, a7};
    half8 h;
    h[0] = (half_t)a0; h[1] = (half_t)a1; h[2] = (half_t)a2; h[3] = (half_t)a3;
    h[4] = (half_t)a4; h[5] = (half_t)a5; h[6] = (half_t)a6; h[7] = (half_t)a7;
    *(half8*)&attnh[rb] = h;
}

extern "C" void kernel_launch(void* const* d_in, const int* in_sizes, int n_in,
                              void* d_out, int out_size, void* d_ws, size_t ws_size,
                              hipStream_t stream) {
    const float* base = (const float*)d_in[0];  // [B,C,T,1]
    const float* x    = (const float*)d_in[1];  // [B,C,T,1]
    const float* top  = (const float*)d_in[2];  // [B,C,S]
    const float* comb = (const float*)d_in[3];  // [B,C,S]
    const float* W    = (const float*)d_in[4];  // [C,C]
    const float* bias = (const float*)d_in[5];  // [C]

    float* out   = (float*)d_out;
    float* ctx   = out;          // [B,C,T] final context output (f32, 33.5MB)
    float* attnf = out + BCT_;   // [B,T,S] attn output (f32, 134MB)

    // fp16 staging overlaid on the ctx region (dead before K4 rewrites it):
    half_t* xT   = (half_t*)d_out;        // [B][T][C] f16
    half_t* topT = xT + BCT_;             // [B][S][C] f16

    // ws layout (~172MB):
    half_t* pws   = (half_t*)d_ws;                    // [B][T][S] f16, 67MB
    half_t* attnh = pws + BTS_;                       // [B][T][S] f16, 67MB
    half_t* combh = attnh + BTS_;                     // [B][C][S] f16, 16.8MB
    half_t* Wh    = combh + (size_t)B_ * C_ * S_;     // [C][C] f16, 0.5MB
    half_t* tgtT  = Wh + (size_t)C_ * C_;             // [B][T][C] f16, 16.8MB
    float*  mArr  = (float*)(tgtT + BCT_);            // [B][16][T] f32, 2MB
    float*  sArr  = mArr + (size_t)B_ * 16 * T_;      // [B][16][T] f32, 2MB

    // pre-passes (2 launches)
    transpose2_cvt_kernel<<<dim3(T_ / 64, C_ / 64, 16), 256, 0, stream>>>(x, top, xT, topT);
    {
        const int n4a = (int)((size_t)B_ * C_ * S_ / 4);
        const int n4tot = n4a + C_ * C_ / 4;
        cvt2_f32_f16_kernel<<<2048, 256, 0, stream>>>(comb, combh, W, Wh, n4a, n4tot);
    }

    // K1: tgtT[b][t][o] = (x^T W^T + b + base)*SCALE   M=T,N=C,K=C
    gemm_f16_db_kernel<1><<<dim3(C_ / 128, T_ / 128, B_), 256, 0, stream>>>(
        xT, Wh, nullptr, tgtT, base, bias,
        T_, C_, C_, (size_t)T_ * C_, 0, (size_t)T_ * C_);

    // k2p: p = exp(logits - m_tile) f16 + per-tile stats   M=T,N=S,K=C
    k2p_kernel<<<dim3(S_ / 128, T_ / 128, B_), 256, 0, stream>>>(
        tgtT, topT, pws, mArr, sArr);

    // k3b: exact normalize -> attn f32 + attnh f16
    k3b_kernel<<<dim3(B_ * T_), 256, 0, stream>>>(pws, mArr, sArr, attnf, attnh);

    // K4: ctx[b][c][t] = combh . attnh                 M=C,N=T,K=S
    gemm_f16_db_kernel<0><<<dim3(T_ / 128, C_ / 128, B_), 256, 0, stream>>>(
        combh, attnh, ctx, nullptr, nullptr, nullptr,
        C_, T_, S_, (size_t)C_ * S_, (size_t)T_ * S_, (size_t)C_ * T_);
}

// Round 6
// 235.184 us; speedup vs baseline: 1.4037x; 1.1110x over previous
//
#include <hip/hip_runtime.h>
#include <cstddef>
#include <cstdint>

#define SCALE_WEIGHT 0.70710678118654752440f

static constexpr int B_ = 8, C_ = 512, T_ = 2048, S_ = 2048;
static constexpr size_t BCT_ = (size_t)B_ * C_ * T_;   // 8.4M  (ctx region elems)
static constexpr size_t BTS_ = (size_t)B_ * T_ * S_;   // 33.5M (attn region elems)

typedef _Float16 half_t;
typedef half_t half8  __attribute__((ext_vector_type(8)));
typedef half_t half4v __attribute__((ext_vector_type(4)));
typedef float  floatx4 __attribute__((ext_vector_type(4)));

// async global->LDS, 16B per lane. LDS dest = wave-uniform base + lane*16.
__device__ __forceinline__ void gload_lds16(const void* g, void* l) {
    __builtin_amdgcn_global_load_lds(
        (const __attribute__((address_space(1))) void*)g,
        (__attribute__((address_space(3))) void*)l, 16, 0, 0);
}

// ---------------------------------------------------------------------------
// merged transpose+convert for x and top: [b][512][2048] f32 -> [b][2048][512] f16
// ---------------------------------------------------------------------------
__global__ __launch_bounds__(256) void transpose2_cvt_kernel(
    const float* __restrict__ x, const float* __restrict__ top,
    half_t* __restrict__ xT, half_t* __restrict__ topT)
{
    __shared__ float tile[64][65];
    const int z = blockIdx.z;
    const float* in = (z < 8) ? x : top;
    half_t* outp = (z < 8) ? xT : topT;
    const int b  = z & 7;
    const int r0 = blockIdx.y * 64, c0 = blockIdx.x * 64;
    const float* ib = in + (size_t)b * C_ * T_;
    half_t* ob = outp + (size_t)b * C_ * T_;
    const int t  = threadIdx.x;
    const int rr = t >> 4, cq = t & 15;
    #pragma unroll
    for (int i = 0; i < 4; ++i) {
        const int r = rr + i * 16;
        float4 v = *(const float4*)&ib[(size_t)(r0 + r) * T_ + c0 + cq * 4];
        tile[cq * 4 + 0][r] = v.x;
        tile[cq * 4 + 1][r] = v.y;
        tile[cq * 4 + 2][r] = v.z;
        tile[cq * 4 + 3][r] = v.w;
    }
    __syncthreads();
    const int cw = t >> 4, rq = (t & 15) * 4;
    #pragma unroll
    for (int i = 0; i < 4; ++i) {
        const int c = cw + i * 16;
        half4v h = {(half_t)tile[c][rq + 0], (half_t)tile[c][rq + 1],
                    (half_t)tile[c][rq + 2], (half_t)tile[c][rq + 3]};
        *(half4v*)&ob[(size_t)(c0 + c) * C_ + r0 + rq] = h;
    }
}

// ---------------------------------------------------------------------------
// merged convert f32 -> f16 for comb and W
// ---------------------------------------------------------------------------
__global__ __launch_bounds__(256) void cvt2_f32_f16_kernel(
    const float* __restrict__ comb, half_t* __restrict__ combh,
    const float* __restrict__ W, half_t* __restrict__ Wh,
    int n4a, int n4tot)
{
    const int stride = gridDim.x * blockDim.x;
    for (int i = blockIdx.x * blockDim.x + threadIdx.x; i < n4tot; i += stride) {
        const float4* src; half4v* dst; int j;
        if (i < n4a) { src = (const float4*)comb; dst = (half4v*)combh; j = i; }
        else         { src = (const float4*)W;    dst = (half4v*)Wh;    j = i - n4a; }
        float4 v = src[j];
        dst[j] = (half4v){(half_t)v.x, (half_t)v.y, (half_t)v.z, (half_t)v.w};
    }
}

// ---------------------------------------------------------------------------
// Unified MFMA fp16 GEMM, 128x128 tile, 4 waves, BK=32, double-buffered LDS
// (32KB -> 4-5 blocks/CU), counted vmcnt(4). Flat grid with XCD pinning:
// b = wgid&7 so each XCD's L2 holds one batch's operand panels.
// A: [M][K] k-contig.  B: [N][K] k-contig.
// EPI 0 (K1): f16 store of (acc + bias[col] + base[b][col][row])*SCALE
// EPI 1 (k2p): per-128-col-tile softmax prep: p=exp(l-m_tile) f16 + (m,sigma)
// EPI 2 (K4s): B-fragments scaled by f[b][st][n] (staged in LDS); f32 C store
// ---------------------------------------------------------------------------
template<int MM, int NN, int KK, int EPI>
__global__ __launch_bounds__(256) void gemm32_kernel(
    const half_t* __restrict__ A, const half_t* __restrict__ Bm,
    size_t sA, size_t sB,
    float* __restrict__ outF, half_t* __restrict__ outH,
    const float* __restrict__ base, const float* __restrict__ bias,
    float* __restrict__ mArr, float* __restrict__ sArr,
    const float* __restrict__ fArr)
{
    constexpr int LDSSZ = (EPI == 1) ? 34816 : ((EPI == 2) ? 40960 : 32768);
    __shared__ __align__(128) char smem[LDSSZ];
    // layout: As[2] @ 0,8K ; Bs[2] @ 16K,24K ; (EPI1: stats @32K; EPI2: f @32K)

    const int tid = threadIdx.x, lane = tid & 63, w = tid >> 6;
    const int wr = w >> 1, wc = w & 1;

    // XCD-pinned flat-grid decode
    const int wgid = blockIdx.x;
    const int b = wgid & 7;
    const int tile = wgid >> 3;
    constexpr int NXT = NN / 128;
    constexpr int NMT = MM / 128;
    int m0, n0;
    if constexpr (EPI == 2) { n0 = (tile / NMT) * 128; m0 = (tile % NMT) * 128; }
    else                    { n0 = (tile % NXT) * 128; m0 = (tile / NXT) * 128; }

    const half_t* Ab = A  + (size_t)b * sA;
    const half_t* Bb = Bm + (size_t)b * sB;

    // staging addrs: chunk = 16 rows x 64B; wave w stages rows [w*32,w*32+32)
    const int lr = lane >> 2, sl = lane & 3;
    const int ks = sl ^ (lr & 3);                 // swizzled source k-slot
    const half_t* aG0 = Ab + (size_t)(m0 + w * 32      + lr) * KK + ks * 8;
    const half_t* aG1 = Ab + (size_t)(m0 + w * 32 + 16 + lr) * KK + ks * 8;
    const half_t* bG0 = Bb + (size_t)(n0 + w * 32      + lr) * KK + ks * 8;
    const half_t* bG1 = Bb + (size_t)(n0 + w * 32 + 16 + lr) * KK + ks * 8;
    const int dOff0 = (w * 32) * 64, dOff1 = (w * 32 + 16) * 64;

    // fragment ds_read byte offsets
    const int fr = lane & 15, kg = lane >> 4;
    const int q4 = kg * 4;
    int aoff[4], boff[4];
    #pragma unroll
    for (int mi = 0; mi < 4; ++mi) {
        const int m = wr * 64 + mi * 16 + fr;
        aoff[mi] = m * 64 + ((kg ^ (m & 3)) << 4);
    }
    #pragma unroll
    for (int nj = 0; nj < 4; ++nj) {
        const int n = wc * 64 + nj * 16 + fr;
        boff[nj] = n * 64 + ((kg ^ (n & 3)) << 4);
    }

    floatx4 acc[4][4];
    #pragma unroll
    for (int mi = 0; mi < 4; ++mi)
        #pragma unroll
        for (int nj = 0; nj < 4; ++nj)
            acc[mi][nj] = (floatx4){0.f, 0.f, 0.f, 0.f};

    auto STAGE = [&](int t, int pg) {
        const int k0 = t * 32;
        char* Ad = smem + pg * 8192;
        char* Bd = smem + 16384 + pg * 8192;
        gload_lds16(aG0 + k0, Ad + dOff0);
        gload_lds16(aG1 + k0, Ad + dOff1);
        gload_lds16(bG0 + k0, Bd + dOff0);
        gload_lds16(bG1 + k0, Bd + dOff1);
    };

    auto COMPUTE = [&](int pg, int t) {
        const char* Ar = smem + pg * 8192;
        const char* Br = smem + 16384 + pg * 8192;
        half8 af[4], bf[4];
        #pragma unroll
        for (int mi = 0; mi < 4; ++mi) af[mi] = *(const half8*)(Ar + aoff[mi]);
        #pragma unroll
        for (int nj = 0; nj < 4; ++nj) bf[nj] = *(const half8*)(Br + boff[nj]);
        if constexpr (EPI == 2) {
            const float* fls = (const float*)(smem + 32768);
            const int st = t >> 2;     // 128-col s-tile index of this K-chunk
            #pragma unroll
            for (int nj = 0; nj < 4; ++nj) {
                const half_t fh = (half_t)fls[st * 128 + wc * 64 + nj * 16 + fr];
                #pragma unroll
                for (int e = 0; e < 8; ++e) bf[nj][e] *= fh;
            }
        }
        #pragma unroll
        for (int mi = 0; mi < 4; ++mi)
            #pragma unroll
            for (int nj = 0; nj < 4; ++nj)
                acc[mi][nj] = __builtin_amdgcn_mfma_f32_16x16x32_f16(
                    af[mi], bf[nj], acc[mi][nj], 0, 0, 0);
    };

    // prologue
    if constexpr (EPI == 2) {
        // stage f[b][16][n0..n0+128) f32 = 8KB into LDS @32K (all waves issue
        // the same 8 loads -> per-wave vmcnt counting stays uniform)
        const float* fB = fArr + (size_t)b * 16 * T_;
        #pragma unroll
        for (int c = 0; c < 8; ++c)
            gload_lds16(fB + (size_t)(2 * c + (lane >> 5)) * T_ + n0 + (lane & 31) * 4,
                        smem + 32768 + c * 1024);
    }
    constexpr int NT = KK / 32;
    STAGE(0, 0);
    int cur = 0;
    #pragma unroll 1
    for (int t = 0; t < NT - 1; ++t) {
        STAGE(t + 1, cur ^ 1);
        __builtin_amdgcn_sched_barrier(0);
        asm volatile("s_waitcnt vmcnt(4)" ::: "memory");  // own tile-t loads done
        __builtin_amdgcn_s_barrier();
        __builtin_amdgcn_sched_barrier(0);
        COMPUTE(cur, t);
        asm volatile("s_waitcnt lgkmcnt(0)" ::: "memory");
        __builtin_amdgcn_sched_barrier(0);
        __builtin_amdgcn_s_barrier();
        __builtin_amdgcn_sched_barrier(0);
        cur ^= 1;
    }
    asm volatile("s_waitcnt vmcnt(0)" ::: "memory");
    __builtin_amdgcn_s_barrier();
    __builtin_amdgcn_sched_barrier(0);
    COMPUTE(cur, NT - 1);

    if constexpr (EPI == 0) {
        // K1: f16 store of (acc + bias + base^T)*SCALE
        half_t* Cb = outH + (size_t)b * ((size_t)MM * NN);
        #pragma unroll
        for (int nj = 0; nj < 4; ++nj) {
            const int col = n0 + wc * 64 + nj * 16 + fr;
            const float bn = bias[col];
            const float* bp = base + ((size_t)b * NN + col) * (size_t)MM;
            #pragma unroll
            for (int mi = 0; mi < 4; ++mi) {
                const int row = m0 + wr * 64 + mi * 16 + q4;
                #pragma unroll
                for (int r = 0; r < 4; ++r) {
                    float v = (acc[mi][nj][r] + bn + bp[row + r]) * SCALE_WEIGHT;
                    Cb[(size_t)(row + r) * NN + col] = (half_t)v;
                }
            }
        }
    } else if constexpr (EPI == 2) {
        // K4s: plain f32 store (ctx)
        float* Cb = outF + (size_t)b * ((size_t)MM * NN);
        #pragma unroll
        for (int mi = 0; mi < 4; ++mi) {
            const int row = m0 + wr * 64 + mi * 16 + q4;
            #pragma unroll
            for (int nj = 0; nj < 4; ++nj) {
                const int col = n0 + wc * 64 + nj * 16 + fr;
                #pragma unroll
                for (int r = 0; r < 4; ++r)
                    Cb[(size_t)(row + r) * NN + col] = acc[mi][nj][r];
            }
        }
    } else {
        // k2p epilogue: tile-max, p=exp(l-m) -> LDS ptile (swizzled), stats,
        // then coalesced half8 global stores.
        __syncthreads();   // all frag ds_reads done block-wide; LDS reusable
        float* rmax = (float*)(smem + 32768);          // [2][128]
        float* rsum = (float*)(smem + 32768 + 1024);   // [2][128]

        #pragma unroll
        for (int mi = 0; mi < 4; ++mi)
            #pragma unroll
            for (int r = 0; r < 4; ++r) {
                float v = fmaxf(fmaxf(acc[mi][0][r], acc[mi][1][r]),
                                fmaxf(acc[mi][2][r], acc[mi][3][r]));
                v = fmaxf(v, __shfl_xor(v, 1));
                v = fmaxf(v, __shfl_xor(v, 2));
                v = fmaxf(v, __shfl_xor(v, 4));
                v = fmaxf(v, __shfl_xor(v, 8));
                if (fr == 0) rmax[wc * 128 + wr * 64 + mi * 16 + q4 + r] = v;
            }
        __syncthreads();

        #pragma unroll
        for (int mi = 0; mi < 4; ++mi)
            #pragma unroll
            for (int r = 0; r < 4; ++r) {
                const int row = wr * 64 + mi * 16 + q4 + r;
                const float mC = fmaxf(rmax[row], rmax[128 + row]);
                float s = 0.f;
                #pragma unroll
                for (int nj = 0; nj < 4; ++nj) {
                    const int col = wc * 64 + nj * 16 + fr;
                    float pv = __expf(acc[mi][nj][r] - mC);
                    s += pv;
                    *(half_t*)(smem + row * 256 + ((col * 2) ^ ((row & 7) << 4))) =
                        (half_t)pv;
                }
                s += __shfl_xor(s, 1);
                s += __shfl_xor(s, 2);
                s += __shfl_xor(s, 4);
                s += __shfl_xor(s, 8);
                if (fr == 0) rsum[wc * 128 + row] = s;
            }
        __syncthreads();

        if (tid < 128) {
            const float m = fmaxf(rmax[tid], rmax[128 + tid]);
            const float s = rsum[tid] + rsum[128 + tid];
            const size_t si = ((size_t)(b * 16 + (n0 >> 7))) * (size_t)MM + m0 + tid;
            mArr[si] = m;
            sArr[si] = s;
        }

        half_t* Pb = outH + ((size_t)b * MM + m0) * (size_t)NN + n0;
        const int rlo = tid >> 4, slot = tid & 15;
        #pragma unroll
        for (int pp = 0; pp < 8; ++pp) {
            const int row = pp * 16 + rlo;
            const int lb = row * 256 + ((slot * 16) ^ ((row & 7) << 4));
            half8 v = *(const half8*)(smem + lb);
            *(half8*)&Pb[(size_t)row * NN + slot * 8] = v;
        }
    }
}

// ---------------------------------------------------------------------------
// kf: f[b][st][t] = exp(m_st - m_fin) / sigma  (exact tile-stat combine)
// ---------------------------------------------------------------------------
__global__ __launch_bounds__(256) void kf_kernel(
    const float* __restrict__ mArr, const float* __restrict__ sArr,
    float* __restrict__ fArr)
{
    const int gid = blockIdx.x * 256 + threadIdx.x;   // b*2048 + t
    const int b = gid >> 11, t = gid & 2047;
    float mv[16];
    float mfin = -3.0e38f;
    #pragma unroll
    for (int j = 0; j < 16; ++j) {
        mv[j] = mArr[((size_t)(b * 16 + j)) * T_ + t];
        mfin = fmaxf(mfin, mv[j]);
    }
    float sig = 0.f;
    #pragma unroll
    for (int j = 0; j < 16; ++j)
        sig += sArr[((size_t)(b * 16 + j)) * T_ + t] * __expf(mv[j] - mfin);
    const float inv = 1.f / sig;
    #pragma unroll
    for (int j = 0; j < 16; ++j)
        fArr[((size_t)(b * 16 + j)) * T_ + t] = __expf(mv[j] - mfin) * inv;
}

// ---------------------------------------------------------------------------
// k3n: attnf[b][t][s] = p[b][t][s] * f[b][s>>7][t]   (f32 output only)
// ---------------------------------------------------------------------------
__global__ __launch_bounds__(256) void k3n_kernel(
    const half_t* __restrict__ P, const float* __restrict__ fArr,
    float* __restrict__ attnf)
{
    const int bid = blockIdx.x;           // b*2048 + t
    const int b = bid >> 11, t = bid & 2047;
    const int tid = threadIdx.x;
    const float f = fArr[((size_t)(b * 16 + (tid >> 4))) * T_ + t];
    const size_t rb = (size_t)bid * S_ + tid * 8;
    half8 v = *(const half8*)&P[rb];
    float4 o0 = {(float)v[0] * f, (float)v[1] * f, (float)v[2] * f, (float)v[3] * f};
    float4 o1 = {(float)v[4] * f, (float)v[5] * f, (float)v[6] * f, (float)v[7] * f};
    *(float4*)&attnf[rb]     = o0;
    *(float4*)&attnf[rb + 4] = o1;
}

extern "C" void kernel_launch(void* const* d_in, const int* in_sizes, int n_in,
                              void* d_out, int out_size, void* d_ws, size_t ws_size,
                              hipStream_t stream) {
    const float* base = (const float*)d_in[0];  // [B,C,T,1]
    const float* x    = (const float*)d_in[1];  // [B,C,T,1]
    const float* top  = (const float*)d_in[2];  // [B,C,S]
    const float* comb = (const float*)d_in[3];  // [B,C,S]
    const float* W    = (const float*)d_in[4];  // [C,C]
    const float* bias = (const float*)d_in[5];  // [C]

    float* out   = (float*)d_out;
    float* ctx   = out;          // [B,C,T] final context output (f32, 33.5MB)
    float* attnf = out + BCT_;   // [B,T,S] attn output (f32, 134MB)

    // fp16 staging overlaid on the ctx region (dead before K4s rewrites it):
    half_t* xT   = (half_t*)d_out;        // [B][T][C] f16
    half_t* topT = xT + BCT_;             // [B][S][C] f16

    // ws layout (~105MB):
    half_t* pws   = (half_t*)d_ws;                    // [B][T][S] f16, 67MB
    half_t* combh = pws + BTS_;                       // [B][C][S] f16, 16.8MB
    half_t* Wh    = combh + (size_t)B_ * C_ * S_;     // [C][C] f16, 0.5MB
    half_t* tgtT  = Wh + (size_t)C_ * C_;             // [B][T][C] f16, 16.8MB
    float*  mArr  = (float*)(tgtT + BCT_);            // [B][16][T] f32, 1MB
    float*  sArr  = mArr + (size_t)B_ * 16 * T_;      // [B][16][T] f32, 1MB
    float*  fArr  = sArr + (size_t)B_ * 16 * T_;      // [B][16][T] f32, 1MB

    // pre-passes
    transpose2_cvt_kernel<<<dim3(T_ / 64, C_ / 64, 16), 256, 0, stream>>>(x, top, xT, topT);
    {
        const int n4a = (int)((size_t)B_ * C_ * S_ / 4);
        const int n4tot = n4a + C_ * C_ / 4;
        cvt2_f32_f16_kernel<<<2048, 256, 0, stream>>>(comb, combh, W, Wh, n4a, n4tot);
    }

    // K1: tgtT[b][t][o] = (x^T W^T + b + base)*SCALE   M=T,N=C,K=C (sB=0: shared W)
    gemm32_kernel<2048, 512, 512, 0><<<512, 256, 0, stream>>>(
        xT, Wh, (size_t)T_ * C_, 0,
        nullptr, tgtT, base, bias, nullptr, nullptr, nullptr);

    // k2p: p = exp(logits - m_tile) f16 + per-tile stats   M=T,N=S,K=C
    gemm32_kernel<2048, 2048, 512, 1><<<2048, 256, 0, stream>>>(
        tgtT, topT, (size_t)T_ * C_, (size_t)S_ * C_,
        nullptr, pws, nullptr, nullptr, mArr, sArr, nullptr);

    // kf: exact stat combine -> f[b][st][t]
    kf_kernel<<<64, 256, 0, stream>>>(mArr, sArr, fArr);

    // k3n: attnf = p * f  (f32 attn output)
    k3n_kernel<<<B_ * T_, 256, 0, stream>>>(pws, fArr, attnf);

    // K4s: ctx[b][c][t] = sum_s comb[c][s] * (p[t][s]*f[st][t])   M=C,N=T,K=S
    gemm32_kernel<512, 2048, 2048, 2><<<512, 256, 0, stream>>>(
        combh, pws, (size_t)C_ * S_, (size_t)T_ * S_,
        ctx, nullptr, nullptr, nullptr, nullptr, nullptr, fArr);
}